// Round 8
// baseline (379.681 us; speedup 1.0000x reference)
//
#include <hip/hip_runtime.h>
#include <math.h>

#define N_NODES 100000
#define N_EDGES 1600000
#define NBLK 391   // ceil(100000/256)
#define PLANE_U32 800000        // dwords per 16-feat plane (100000 nodes * 8 dwords)
#define PLANE_U16 1600000       // shorts per plane

typedef __attribute__((ext_vector_type(8))) short bf16x8;   // MFMA A/B frag (8 bf16)
typedef __attribute__((ext_vector_type(4))) float f32x4;    // MFMA C/D frag

__device__ __forceinline__ unsigned short f2bf(float f) {   // RNE fp32->bf16
    unsigned int u = __float_as_uint(f);
    u += 0x7FFF + ((u >> 16) & 1);
    return (unsigned short)(u >> 16);
}
__device__ __forceinline__ float bf_lo(unsigned int u) { return __uint_as_float(u << 16); }
__device__ __forceinline__ float bf_hi(unsigned int u) { return __uint_as_float(u & 0xFFFF0000u); }

// ---------------- CSR build ----------------

__global__ __launch_bounds__(256) void zero_cnt_kernel(int* __restrict__ cnt) {
    int i = blockIdx.x * 256 + threadIdx.x;
    if (i < N_NODES) cnt[i] = 0;
}

// enc[e] = src | (rank<<17): src < 2^17, rank < 2^15 (max in-deg ~45 for Poisson(16)).
__global__ __launch_bounds__(256) void deg_count_rank_kernel(const int* __restrict__ src,
                                                             const int* __restrict__ dst,
                                                             int* __restrict__ cnt,
                                                             int* __restrict__ enc) {
    int e = blockIdx.x * 256 + threadIdx.x;
    if (e < N_EDGES) {
        int r = atomicAdd(&cnt[dst[e]], 1);
        enc[e] = src[e] | (r << 17);
    }
}

// Fused: dis[i] = rsqrt(deg+1), then per-block exclusive scan of cnt (+ block totals).
__global__ __launch_bounds__(256) void scan_blk_dis_kernel(int* __restrict__ cnt,
                                                           int* __restrict__ blk,
                                                           float* __restrict__ dis) {
    __shared__ int s[256];
    int t = threadIdx.x, i = blockIdx.x * 256 + t;
    int v = (i < N_NODES) ? cnt[i] : 0;
    if (i < N_NODES) dis[i] = rsqrtf((float)v + 1.0f);
    s[t] = v;
    __syncthreads();
    for (int off = 1; off < 256; off <<= 1) {
        int u = (t >= off) ? s[t - off] : 0;
        __syncthreads();
        s[t] += u;
        __syncthreads();
    }
    if (i < N_NODES) cnt[i] = s[t] - v;           // exclusive within block
    if (t == 255) blk[blockIdx.x] = s[255];
}

__global__ __launch_bounds__(512) void scan_top_kernel(int* __restrict__ blk) {
    __shared__ int s[512];
    int t = threadIdx.x;
    int v = (t < NBLK) ? blk[t] : 0;
    s[t] = v;
    __syncthreads();
    for (int off = 1; off < 512; off <<= 1) {
        int u = (t >= off) ? s[t - off] : 0;
        __syncthreads();
        s[t] += u;
        __syncthreads();
    }
    if (t < NBLK) blk[t] = s[t] - v;
}

// start(d) = cnt[d] + blk[d>>8]. Atomic-free placement.
__global__ __launch_bounds__(256) void place_kernel(const int* __restrict__ dst,
                                                    const int* __restrict__ enc,
                                                    const int* __restrict__ cnt,
                                                    const int* __restrict__ blk,
                                                    int* __restrict__ col) {
    int e = blockIdx.x * 256 + threadIdx.x;
    int d = dst[e];
    int v = enc[e];
    col[cnt[d] + blk[d >> 8] + (v >> 17)] = v & 0x1FFFF;
}

// ---------------- converts: x -> plane-major bf16, W1T/W2T -> bf16 ----------------
// xb plane f (16 feats) is a contiguous 3.2 MB block: xb[f*PLANE + node*16 + (feat%16)].

__global__ __launch_bounds__(256) void convert_xw_kernel(const float* __restrict__ x,
                                                         const float* __restrict__ W1,
                                                         const float* __restrict__ W2,
                                                         ushort* __restrict__ xb,
                                                         ushort* __restrict__ W1T,
                                                         ushort* __restrict__ W2T) {
    if (blockIdx.x < 12500) {
        int i = blockIdx.x * 256 + threadIdx.x;   // one float4 -> 4 bf16
        int node = i >> 5;
        int c = (i & 31) << 2;                    // feat start: 0..124
        float4 v = *(const float4*)&x[i * 4];
        ushort4 o;
        o.x = f2bf(v.x); o.y = f2bf(v.y); o.z = f2bf(v.z); o.w = f2bf(v.w);
        *(ushort4*)&xb[(c >> 4) * PLANE_U16 + node * 16 + (c & 15)] = o;
    } else {
        int j = (blockIdx.x - 12500) * 256 + threadIdx.x;   // 72 blocks * 256 = 18432
        if (j < 16384) {
            int k = j >> 7, n = j & 127;                     // W1[k][n] -> W1T[n][k]
            W1T[n * 128 + k] = f2bf(W1[j]);
        } else {
            int q = j - 16384;                               // 2048 elements
            int k = q >> 4, n = q & 15;                      // W2[k][n] -> W2T[n][k]
            W2T[n * 128 + k] = f2bf(W2[q]);
        }
    }
}

// ---------------- layer-1 aggregation (feature-sliced, XCD-pinned) ----------------
// slice = blockIdx % 8 (XCD round-robin): each XCD touches ONE 3.2 MB xb plane -> L2-resident.
// Block: 32 nodes x 8 lanes; lane owns 1 dword (2 feats). col/dis broadcast across a node's lanes.

__global__ __launch_bounds__(256) void gather1_kernel(const int* __restrict__ col,
                                                      const int* __restrict__ cnt,
                                                      const int* __restrict__ blk,
                                                      const float* __restrict__ dis,
                                                      const unsigned int* __restrict__ xb,
                                                      unsigned int* __restrict__ xa) {
    int t = threadIdx.x;
    int slice = blockIdx.x & 7;                  // XCD pin (speed heuristic only)
    int grp = blockIdx.x >> 3;                   // 3125 groups * 32 = 100000 exact
    int node = grp * 32 + (t >> 3);
    int j = t & 7;
    const unsigned int* xp = xb + slice * PLANE_U32;
    float dn = dis[node];
    int beg = cnt[node] + blk[node >> 8];
    int end = (node == N_NODES - 1) ? N_EDGES : cnt[node + 1] + blk[(node + 1) >> 8];
    unsigned int su = xp[node * 8 + j];
    float a0x = bf_lo(su) * dn, a0y = bf_hi(su) * dn;
    float a1x = 0.f, a1y = 0.f, a2x = 0.f, a2y = 0.f, a3x = 0.f, a3y = 0.f;
    float a4x = 0.f, a4y = 0.f, a5x = 0.f, a5y = 0.f, a6x = 0.f, a6y = 0.f, a7x = 0.f, a7y = 0.f;
    int k = beg;
    for (; k + 8 <= end; k += 8) {
        int s0 = col[k], s1 = col[k + 1], s2 = col[k + 2], s3 = col[k + 3];
        int s4 = col[k + 4], s5 = col[k + 5], s6 = col[k + 6], s7 = col[k + 7];
        float w0 = dis[s0], w1 = dis[s1], w2 = dis[s2], w3 = dis[s3];
        float w4 = dis[s4], w5 = dis[s5], w6 = dis[s6], w7 = dis[s7];
        unsigned int u0 = xp[s0 * 8 + j], u1 = xp[s1 * 8 + j];
        unsigned int u2 = xp[s2 * 8 + j], u3 = xp[s3 * 8 + j];
        unsigned int u4 = xp[s4 * 8 + j], u5 = xp[s5 * 8 + j];
        unsigned int u6 = xp[s6 * 8 + j], u7 = xp[s7 * 8 + j];
        a0x += bf_lo(u0) * w0; a0y += bf_hi(u0) * w0;
        a1x += bf_lo(u1) * w1; a1y += bf_hi(u1) * w1;
        a2x += bf_lo(u2) * w2; a2y += bf_hi(u2) * w2;
        a3x += bf_lo(u3) * w3; a3y += bf_hi(u3) * w3;
        a4x += bf_lo(u4) * w4; a4y += bf_hi(u4) * w4;
        a5x += bf_lo(u5) * w5; a5y += bf_hi(u5) * w5;
        a6x += bf_lo(u6) * w6; a6y += bf_hi(u6) * w6;
        a7x += bf_lo(u7) * w7; a7y += bf_hi(u7) * w7;
    }
    for (; k + 4 <= end; k += 4) {
        int s0 = col[k], s1 = col[k + 1], s2 = col[k + 2], s3 = col[k + 3];
        float w0 = dis[s0], w1 = dis[s1], w2 = dis[s2], w3 = dis[s3];
        unsigned int u0 = xp[s0 * 8 + j], u1 = xp[s1 * 8 + j];
        unsigned int u2 = xp[s2 * 8 + j], u3 = xp[s3 * 8 + j];
        a0x += bf_lo(u0) * w0; a0y += bf_hi(u0) * w0;
        a1x += bf_lo(u1) * w1; a1y += bf_hi(u1) * w1;
        a2x += bf_lo(u2) * w2; a2y += bf_hi(u2) * w2;
        a3x += bf_lo(u3) * w3; a3y += bf_hi(u3) * w3;
    }
    for (; k < end; ++k) {
        int s = col[k];
        float w = dis[s];
        unsigned int u = xp[s * 8 + j];
        a0x += bf_lo(u) * w; a0y += bf_hi(u) * w;
    }
    float rx = (((a0x + a1x) + (a2x + a3x)) + ((a4x + a5x) + (a6x + a7x))) * dn;
    float ry = (((a0y + a1y) + (a2y + a3y)) + ((a4y + a5y) + (a6y + a7y))) * dn;
    xa[slice * PLANE_U32 + node * 8 + j] =       // coalesced: 1 KB contiguous per 32-node group
        (unsigned int)f2bf(rx) | ((unsigned int)f2bf(ry) << 16);
}

// ---------------- fused MLP: h2 = relu(xa@W1 + b1) @ W2, h2 emitted as bf16 ----------------
// xa is plane-major: feats [kk*32+quad*8, +8) live in plane 2*kk+(quad>>1), offset (quad&1)*16B.

__global__ __launch_bounds__(256) void mlp_kernel(const ushort* __restrict__ xa,
                                                  const ushort* __restrict__ W1T,
                                                  const float* __restrict__ b1,
                                                  const ushort* __restrict__ W2T,
                                                  ushort* __restrict__ h2b) {
    __shared__ ushort sh[4][16][136];   // 136: keeps ds_read_b128 16B-aligned, banks spread
    int t = threadIdx.x;
    int wave = t >> 6, lane = t & 63;
    int l = lane & 15, quad = lane >> 4;
    int m0 = blockIdx.x * 64 + wave * 16;        // 1563*64 = 100032; waves past end idle
    bool valid = (m0 < N_NODES);                 // whole-wave predicate (no early return!)
    int row = valid ? (m0 + l) : 0;

    f32x4 acc[8] = {};
    #pragma unroll
    for (int kk = 0; kk < 4; ++kk) {
        int plane = 2 * kk + (quad >> 1);
        bf16x8 a = *(const bf16x8*)&xa[plane * PLANE_U16 + row * 16 + (quad & 1) * 8];
        #pragma unroll
        for (int nt = 0; nt < 8; ++nt) {
            bf16x8 b = *(const bf16x8*)&W1T[(nt * 16 + l) * 128 + kk * 32 + quad * 8];
            acc[nt] = __builtin_amdgcn_mfma_f32_16x16x32_bf16(a, b, acc[nt], 0, 0, 0);
        }
    }
    #pragma unroll
    for (int nt = 0; nt < 8; ++nt) {
        float bias = b1[nt * 16 + l];
        #pragma unroll
        for (int r = 0; r < 4; ++r)
            sh[wave][quad * 4 + r][nt * 16 + l] = f2bf(fmaxf(acc[nt][r] + bias, 0.0f));
    }
    __syncthreads();   // all waves present — orders LDS writes->reads

    f32x4 acc2 = {};
    #pragma unroll
    for (int kk = 0; kk < 4; ++kk) {
        bf16x8 a2 = *(const bf16x8*)&sh[wave][l][kk * 32 + quad * 8];
        bf16x8 bw = *(const bf16x8*)&W2T[l * 128 + kk * 32 + quad * 8];
        acc2 = __builtin_amdgcn_mfma_f32_16x16x32_bf16(a2, bw, acc2, 0, 0, 0);
    }
    if (valid) {
        #pragma unroll
        for (int r = 0; r < 4; ++r)
            h2b[(m0 + quad * 4 + r) * 16 + l] = f2bf(acc2[r]);   // h2[m][n=l]
    }
}

// ---------------- layer-2 gather + bias + log-softmax (bf16 h2 table, 8 lanes/node) ----------------

__global__ __launch_bounds__(256) void gather2_lsm_kernel(const int* __restrict__ col,
                                                          const int* __restrict__ cnt,
                                                          const int* __restrict__ blk,
                                                          const float* __restrict__ dis,
                                                          const unsigned int* __restrict__ h2p,
                                                          const float* __restrict__ b2,
                                                          float* __restrict__ out) {
    int t = threadIdx.x;
    int node = blockIdx.x * 32 + (t >> 3);       // 3125 * 32 = 100000 exact
    int c = t & 7;                               // class pair: (2c, 2c+1)
    float dn = dis[node];
    int beg = cnt[node] + blk[node >> 8];
    int end = (node == N_NODES - 1) ? N_EDGES : cnt[node + 1] + blk[(node + 1) >> 8];
    unsigned int su = h2p[node * 8 + c];
    float a0x = bf_lo(su) * dn, a0y = bf_hi(su) * dn;    // self-loop term
    float a1x = 0.f, a1y = 0.f, a2x = 0.f, a2y = 0.f, a3x = 0.f, a3y = 0.f;
    int k = beg;
    for (; k + 4 <= end; k += 4) {
        int s0 = col[k], s1 = col[k + 1], s2 = col[k + 2], s3 = col[k + 3];
        float w0 = dis[s0], w1 = dis[s1], w2 = dis[s2], w3 = dis[s3];
        unsigned int u0 = h2p[s0 * 8 + c], u1 = h2p[s1 * 8 + c];
        unsigned int u2 = h2p[s2 * 8 + c], u3 = h2p[s3 * 8 + c];
        a0x += bf_lo(u0) * w0; a0y += bf_hi(u0) * w0;
        a1x += bf_lo(u1) * w1; a1y += bf_hi(u1) * w1;
        a2x += bf_lo(u2) * w2; a2y += bf_hi(u2) * w2;
        a3x += bf_lo(u3) * w3; a3y += bf_hi(u3) * w3;
    }
    for (; k < end; ++k) {
        int s = col[k];
        float w = dis[s];
        unsigned int u = h2p[s * 8 + c];
        a0x += bf_lo(u) * w; a0y += bf_hi(u) * w;
    }
    float2 bb = ((const float2*)b2)[c];
    float v0 = ((a0x + a1x) + (a2x + a3x)) * dn + bb.x;
    float v1 = ((a0y + a1y) + (a2y + a3y)) * dn + bb.y;
    float m = fmaxf(v0, v1);
    #pragma unroll
    for (int off = 1; off < 8; off <<= 1) m = fmaxf(m, __shfl_xor(m, off, 8));
    float ssum = expf(v0 - m) + expf(v1 - m);
    #pragma unroll
    for (int off = 1; off < 8; off <<= 1) ssum += __shfl_xor(ssum, off, 8);
    float lg = m + logf(ssum);
    ((float2*)out)[node * 8 + c] = make_float2(v0 - lg, v1 - lg);
}

// ---------------- launch ----------------

extern "C" void kernel_launch(void* const* d_in, const int* in_sizes, int n_in,
                              void* d_out, int out_size, void* d_ws, size_t ws_size,
                              hipStream_t stream) {
    const float* x  = (const float*)d_in[0];
    const int*   ei = (const int*)d_in[1];
    const float* W1 = (const float*)d_in[2];
    const float* b1 = (const float*)d_in[3];
    const float* W2 = (const float*)d_in[4];
    const float* b2 = (const float*)d_in[5];
    float* out = (float*)d_out;

    const int* src = ei;              // edge_index[0]
    const int* dst = ei + N_EDGES;    // edge_index[1]

    // workspace (bytes), TOTAL = 58,440,960 (unchanged, proven safe R2-R7).
    // offset 0 timeline: enc (CSR) -> xb planes (convert->gather1) -> h2b (mlp->gather2)
    char* ws = (char*)d_ws;
    int*    enc = (int*)   (ws + 0);            //  6,400,000
    ushort* xb  = (ushort*)(ws + 0);            // 25,600,000 (8 planes x 3.2 MB)
    ushort* h2b = (ushort*)(ws + 0);            //  3,200,000
    ushort* xa  = (ushort*)(ws + 25600000);     // 25,600,000 (8 planes x 3.2 MB)
    int*    col = (int*)   (ws + 51200000);     //  6,400,000
    float*  dis = (float*) (ws + 57600000);     //    400,000
    int*    cnt = (int*)   (ws + 58000000);     //    400,000
    int*    blk = (int*)   (ws + 58400000);     //      1,564
    ushort* W1T = (ushort*)(ws + 58404096);     //     32,768
    ushort* W2T = (ushort*)(ws + 58436864);     //      4,096

    zero_cnt_kernel      <<<NBLK, 256, 0, stream>>>(cnt);
    deg_count_rank_kernel<<<N_EDGES / 256, 256, 0, stream>>>(src, dst, cnt, enc);
    scan_blk_dis_kernel  <<<NBLK, 256, 0, stream>>>(cnt, blk, dis);
    scan_top_kernel      <<<1, 512, 0, stream>>>(blk);
    place_kernel         <<<N_EDGES / 256, 256, 0, stream>>>(dst, enc, cnt, blk, col);

    convert_xw_kernel    <<<12572, 256, 0, stream>>>(x, W1, W2, xb, W1T, W2T);  // after place (enc dead)

    gather1_kernel       <<<25000, 256, 0, stream>>>(col, cnt, blk, dis,
                                                     (const unsigned int*)xb,
                                                     (unsigned int*)xa);
    mlp_kernel           <<<1563, 256, 0, stream>>>(xa, W1T, b1, W2T, h2b);     // h2b overwrites dead xb
    gather2_lsm_kernel   <<<3125, 256, 0, stream>>>(col, cnt, blk, dis,
                                                    (const unsigned int*)h2b, b2, out);
}